// Round 7
// baseline (377.028 us; speedup 1.0000x reference)
//
#include <hip/hip_runtime.h>
#include <hip/hip_bf16.h>
#include <math.h>

#define HW2 262144              // 512*512
#define TWO_PI     6.28318530717958647693f
#define INV_TWO_PI 0.15915494309189533577f
#define LOG2E      1.44269504088896340736f

typedef float  f32x4  __attribute__((ext_vector_type(4)));
typedef short  s16x8  __attribute__((ext_vector_type(8)));
typedef unsigned short ushort_t;

template <int I> struct ic { static constexpr int v = I; };
template <int I, int N, typename F>
__device__ __forceinline__ void sfor(F&& f) {
    if constexpr (I < N) { f(ic<I>{}); sfor<I + 1, N>(f); }
}

__device__ __forceinline__ ushort_t bf16_hi(float v) {
    __hip_bfloat16 h = __float2bfloat16(v);
    return __builtin_bit_cast(ushort_t, h);
}
__device__ __forceinline__ float bf16_tof(ushort_t u) {
    unsigned int x = ((unsigned int)u) << 16;
    return __builtin_bit_cast(float, x);
}

// k-slot permutation: stored k (KC*32 + g*8 + j) reads source channel
// KC*32 + (j>>2)*16 + g*4 + (j&3). With W columns stored in this order,
// the next-layer B fragment element j of chunk KC at lane group g is
// acc[2KC + (j>>2)][j&3] ON THE SAME LANE -> no LDS/shuffle relayout.
__device__ __forceinline__ int kperm(int ks) {
    int KC = ks >> 5, g = (ks >> 3) & 3, j = ks & 7;
    return KC * 32 + (j >> 2) * 16 + g * 4 + (j & 3);
}

// ---- ws layout (bytes) ----
// pcq    f32[5][64][12] @ 0      expanded gabor constants (15360 B)
//   per channel: [a,b,c,d, e,f,w0r,w1r, br,0,0,0]
// whi    u16[4][64][64] @ 15360  lin_w hi-bf16, [c_out][k_perm]
// wlo    u16[4][64][64] @ 48128  lin_w lo-bf16
// wouthi u16[16][64]    @ 80896  out_w hi (rows 3..15 zero), k_perm cols
// woutlo u16[16][64]    @ 82944
#define WS_WHI  15360
#define WS_WLO  48128
#define WS_WOH  80896
#define WS_WOL  82944

__global__ void gabor_pre(const float* __restrict__ filt_w,
                          const float* __restrict__ filt_b,
                          const float* __restrict__ mu,
                          const float* __restrict__ gamma,
                          const float* __restrict__ theta,
                          const float* __restrict__ lin_w,
                          const float* __restrict__ out_w,
                          float* __restrict__ pcq,
                          ushort_t* __restrict__ whi, ushort_t* __restrict__ wlo,
                          ushort_t* __restrict__ wouthi, ushort_t* __restrict__ woutlo) {
    int t = blockIdx.x * 256 + threadIdx.x;
    if (t < 320) {
        int i = t;
        float ang = TWO_PI * theta[i];
        float cs = cosf(ang), sn = sinf(ang);
        float g0 = gamma[i*2+0], g1 = gamma[i*2+1];
        float g0s = g0*g0, g1s = g1*g1;
        float cs2 = cs*cs, sn2 = sn*sn;
        float A = -0.5f * LOG2E * (g0s*cs2 + g1s*sn2);
        float B = -LOG2E * (cs*sn*(g0s - g1s));
        float C = -0.5f * LOG2E * (g0s*sn2 + g1s*cs2);
        float m0 = mu[i*2+0], m1 = mu[i*2+1];
        float* o = pcq + i*12;
        o[0] = A;  o[1] = B;  o[2] = C;
        o[3] = -(2.0f*A*m0 + B*m1);
        o[4] = -(B*m0 + 2.0f*C*m1);
        o[5] = A*m0*m0 + B*m0*m1 + C*m1*m1;
        o[6] = filt_w[i*2+0] * INV_TWO_PI;
        o[7] = filt_w[i*2+1] * INV_TWO_PI;
        o[8] = filt_b[i] * INV_TWO_PI;
        o[9] = 0.0f; o[10] = 0.0f; o[11] = 0.0f;
    } else if (t < 320 + 16384) {
        int i  = t - 320;                      // l*4096 + c*64 + ks
        int ks = i & 63;
        float w = lin_w[(i - ks) + kperm(ks)];
        ushort_t h = bf16_hi(w);
        whi[i] = h;
        wlo[i] = bf16_hi(w - bf16_tof(h));
    } else if (t < 320 + 16384 + 1024) {
        int i  = t - (320 + 16384);            // m*64 + ks
        int m  = i >> 6, ks = i & 63;
        float w = (m < 3) ? out_w[m*64 + kperm(ks)] : 0.0f;
        ushort_t h = bf16_hi(w);
        wouthi[i] = h;
        woutlo[i] = bf16_hi(w - bf16_tof(h));
    }
}

// expanded gabor eval: x02,x11,x12 shared per pixel
__device__ __forceinline__ float geval(f32x4 qa, f32x4 qb, float br,
                                       float x0, float x1,
                                       float x02, float x11, float x12) {
    float t = fmaf(qa[0], x02, fmaf(qa[1], x11,
              fmaf(qa[2], x12, fmaf(qa[3], x0, fmaf(qb[0], x1, qb[1])))));
    float e  = __builtin_amdgcn_exp2f(t);
    float sa = fmaf(qb[2], x0, fmaf(qb[3], x1, br));
    return e * __builtin_amdgcn_sinf(sa);
}

// One wave = 64 pixels, 4 independent waves per 256-block. No LDS, no
// barriers: h lives entirely in registers as B-fragments bh/bl[NI][KC],
// rebuilt each layer from acc via the kperm identity (see kperm()).
// GEMM per layer: D[c,px] = W[c,k] h[k,px], mfma_f32_16x16x32_bf16,
// 3-product split-bf16 (ah*bh + ah*bl + al*bh; al*bl ~2^-18 dropped).
//   A frag: m = lane&15, k-slot = (lane>>4)*8 + j  (W rows, permuted cols)
//   B frag: n = lane&15 (pixel), k-slot = (lane>>4)*8 + j
//   C/D:    col n = lane&15 (pixel), row m = (lane>>4)*4 + reg (channel)
// NI tiles streamed (MFMA -> epilogue -> frag rebuild per tile) to cap
// live VGPRs at frags(64) + one acc(16) + temps.
__global__ __launch_bounds__(256, 3) void gabor_mfma(
    const float* __restrict__ x, const float* __restrict__ lin_b,
    const float* __restrict__ out_b, const float* __restrict__ pcq,
    const ushort_t* __restrict__ whi, const ushort_t* __restrict__ wlo,
    const ushort_t* __restrict__ wouthi, const ushort_t* __restrict__ woutlo,
    float* __restrict__ out) {
    const int lane = threadIdx.x & 63;
    const int wid  = threadIdx.x >> 6;
    const int g    = lane >> 4;
    const int lm   = lane & 15;
    const int base = blockIdx.x * 256 + wid * 64;

    f32x4 x0v, x1v, x02v, x11v, x12v;
    int pixo[4];
    sfor<0, 4>([&](auto NI) {
        int P  = base + NI.v*16 + lm;
        int bb = P >> 18, pix = P & (HW2 - 1);
        const float* xb = x + bb*(2*HW2) + pix;
        float a = xb[0], b = xb[HW2];
        x0v[NI.v] = a;  x1v[NI.v] = b;
        x02v[NI.v] = a*a;  x11v[NI.v] = a*b;  x12v[NI.v] = b*b;
        pixo[NI.v] = bb*(3*HW2) + pix;
    });

    s16x8 bh[4][2], bl[4][2];   // h as B-fragments, hi/lo split

    // build frags for tile NI from 4 epilogue f32x4's (MI=0..3)
    auto mkfrag = [&](f32x4 vA, f32x4 vB, s16x8& fh, s16x8& fl) {
        sfor<0, 4>([&](auto R) {
            ushort_t hA = bf16_hi(vA[R.v]);
            ushort_t hB = bf16_hi(vB[R.v]);
            fh[R.v]     = (short)hA;
            fh[R.v + 4] = (short)hB;
            fl[R.v]     = (short)bf16_hi(vA[R.v] - bf16_tof(hA));
            fl[R.v + 4] = (short)bf16_hi(vB[R.v] - bf16_tof(hB));
        });
    };

    // ---- layer 0: h0 = gabor at C/D positions, straight into frags ----
    sfor<0, 4>([&](auto NI) {
        f32x4 v[4];
        sfor<0, 4>([&](auto MI) {
            sfor<0, 4>([&](auto R) {
                const float* q = pcq + (MI.v*16 + 4*g + R.v)*12;
                f32x4 qa = *(const f32x4*)q, qb = *(const f32x4*)(q + 4);
                v[MI.v][R.v] = geval(qa, qb, q[8], x0v[NI.v], x1v[NI.v],
                                     x02v[NI.v], x11v[NI.v], x12v[NI.v]);
            });
        });
        mkfrag(v[0], v[1], bh[NI.v][0], bl[NI.v][0]);
        mkfrag(v[2], v[3], bh[NI.v][1], bl[NI.v][1]);
    });

    // ---- layers 1..4: nh = gabor * (W h + b) ----
#pragma unroll 1
    for (int l = 1; l <= 4; ++l) {
        const ushort_t* whl = whi + (l-1)*4096;
        const ushort_t* wll = wlo + (l-1)*4096;
        const float*    bv  = lin_b + (l-1)*64;
        const float*    pcl = pcq + l*768;
        sfor<0, 4>([&](auto NI) {
            constexpr int ni = NI.v;
            f32x4 acc[4];
            sfor<0, 4>([&](auto MI) {
                acc[MI.v] = *(const f32x4*)(bv + MI.v*16 + 4*g);
            });
            sfor<0, 2>([&](auto KC) {
                sfor<0, 4>([&](auto MI) {
                    int off = (MI.v*16 + lm)*64 + KC.v*32 + g*8;
                    s16x8 ah = *(const s16x8*)(whl + off);
                    s16x8 al = *(const s16x8*)(wll + off);
                    f32x4 a = acc[MI.v];
                    a = __builtin_amdgcn_mfma_f32_16x16x32_bf16(ah, bh[ni][KC.v], a, 0, 0, 0);
                    a = __builtin_amdgcn_mfma_f32_16x16x32_bf16(ah, bl[ni][KC.v], a, 0, 0, 0);
                    a = __builtin_amdgcn_mfma_f32_16x16x32_bf16(al, bh[ni][KC.v], a, 0, 0, 0);
                    acc[MI.v] = a;
                });
            });
            f32x4 v[4];
            sfor<0, 4>([&](auto MI) {
                sfor<0, 4>([&](auto R) {
                    const float* q = pcl + (MI.v*16 + 4*g + R.v)*12;
                    f32x4 qa = *(const f32x4*)q, qb = *(const f32x4*)(q + 4);
                    v[MI.v][R.v] = geval(qa, qb, q[8], x0v[ni], x1v[ni],
                                         x02v[ni], x11v[ni], x12v[ni])
                                   * acc[MI.v][R.v];
                });
            });
            mkfrag(v[0], v[1], bh[ni][0], bl[ni][0]);
            mkfrag(v[2], v[3], bh[ni][1], bl[ni][1]);
        });
    }

    // ---- output: out[o,px] = Wout[o,k] h4[k,px] + out_b ----
    float ob0 = out_b[0], ob1 = out_b[1], ob2 = out_b[2];
    sfor<0, 4>([&](auto NI) {
        constexpr int ni = NI.v;
        f32x4 ao = (f32x4)(0.0f);
        sfor<0, 2>([&](auto KC) {
            int off = lm*64 + KC.v*32 + g*8;
            s16x8 ah = *(const s16x8*)(wouthi + off);
            s16x8 al = *(const s16x8*)(woutlo + off);
            ao = __builtin_amdgcn_mfma_f32_16x16x32_bf16(ah, bh[ni][KC.v], ao, 0, 0, 0);
            ao = __builtin_amdgcn_mfma_f32_16x16x32_bf16(ah, bl[ni][KC.v], ao, 0, 0, 0);
            ao = __builtin_amdgcn_mfma_f32_16x16x32_bf16(al, bh[ni][KC.v], ao, 0, 0, 0);
        });
        if (lane < 16) {   // g==0 holds rows 0..3; out channels 0..2
            float* po = out + pixo[ni];
            po[0]     = ao[0] + ob0;
            po[HW2]   = ao[1] + ob1;
            po[2*HW2] = ao[2] + ob2;
        }
    });
}

extern "C" void kernel_launch(void* const* d_in, const int* in_sizes, int n_in,
                              void* d_out, int out_size, void* d_ws, size_t ws_size,
                              hipStream_t stream) {
    const float* x      = (const float*)d_in[0];
    const float* filt_w = (const float*)d_in[1];
    const float* filt_b = (const float*)d_in[2];
    const float* mu     = (const float*)d_in[3];
    const float* gamma  = (const float*)d_in[4];
    const float* theta  = (const float*)d_in[5];
    const float* lin_w  = (const float*)d_in[6];
    const float* lin_b  = (const float*)d_in[7];
    const float* out_w  = (const float*)d_in[8];
    const float* out_b  = (const float*)d_in[9];

    char* ws = (char*)d_ws;
    float*    pcq    = (float*)ws;
    ushort_t* whi    = (ushort_t*)(ws + WS_WHI);
    ushort_t* wlo    = (ushort_t*)(ws + WS_WLO);
    ushort_t* wouthi = (ushort_t*)(ws + WS_WOH);
    ushort_t* woutlo = (ushort_t*)(ws + WS_WOL);

    gabor_pre<<<70, 256, 0, stream>>>(filt_w, filt_b, mu, gamma, theta,
                                      lin_w, out_w, pcq, whi, wlo, wouthi, woutlo);
    gabor_mfma<<<2048, 256, 0, stream>>>(x, lin_b, out_b, pcq, whi, wlo,
                                         wouthi, woutlo, (float*)d_out);
}

// Round 8
// 141.336 us; speedup vs baseline: 2.6676x; 2.6676x over previous
//
#include <hip/hip_runtime.h>
#include <hip/hip_bf16.h>
#include <math.h>

#define HW2 262144              // 512*512
#define TWO_PI     6.28318530717958647693f
#define INV_TWO_PI 0.15915494309189533577f
#define LOG2E      1.44269504088896340736f

typedef float  f32x4  __attribute__((ext_vector_type(4)));
typedef short  s16x8  __attribute__((ext_vector_type(8)));
typedef unsigned short ushort_t;

__device__ __forceinline__ ushort_t bf16_hi(float v) {
    __hip_bfloat16 h = __float2bfloat16(v);
    return __builtin_bit_cast(ushort_t, h);
}
__device__ __forceinline__ float bf16_tof(ushort_t u) {
    unsigned int x = ((unsigned int)u) << 16;
    return __builtin_bit_cast(float, x);
}

// k-slot permutation (verified R7, absmax 6.1e-5): stored k-slot
// (KC*32 + g*8 + j) holds source channel KC*32 + (j>>2)*16 + g*4 + (j&3).
// With W columns stored in this order, next-layer B-frag elem j of chunk KC
// at lane-group g equals acc[2KC + (j>>2)][j&3] ON THE SAME LANE ->
// no LDS / shuffle / barrier relayout between layers.
__device__ __forceinline__ int kperm(int ks) {
    int KC = ks >> 5, g = (ks >> 3) & 3, j = ks & 7;
    return KC * 32 + (j >> 2) * 16 + g * 4 + (j & 3);
}

// ---- ws layout (bytes) ----
// pcq    f32[5][64][12] @ 0      expanded gabor constants
//   per channel: [a,b,c,d, e,f,w0r,w1r, br,0,0,0]
// whi    u16[4][64][64] @ 15360  lin_w hi-bf16, [c_out][k_perm]
// wlo    u16[4][64][64] @ 48128  lin_w lo-bf16
// wouthi u16[16][64]    @ 80896  out_w hi (rows 3..15 zero), k_perm cols
// woutlo u16[16][64]    @ 82944
#define WS_WHI  15360
#define WS_WLO  48128
#define WS_WOH  80896
#define WS_WOL  82944

__global__ void gabor_pre(const float* __restrict__ filt_w,
                          const float* __restrict__ filt_b,
                          const float* __restrict__ mu,
                          const float* __restrict__ gamma,
                          const float* __restrict__ theta,
                          const float* __restrict__ lin_w,
                          const float* __restrict__ out_w,
                          float* __restrict__ pcq,
                          ushort_t* __restrict__ whi, ushort_t* __restrict__ wlo,
                          ushort_t* __restrict__ wouthi, ushort_t* __restrict__ woutlo) {
    int t = blockIdx.x * 256 + threadIdx.x;
    if (t < 320) {
        int i = t;
        float ang = TWO_PI * theta[i];
        float cs = cosf(ang), sn = sinf(ang);
        float g0 = gamma[i*2+0], g1 = gamma[i*2+1];
        float g0s = g0*g0, g1s = g1*g1;
        float cs2 = cs*cs, sn2 = sn*sn;
        float A = -0.5f * LOG2E * (g0s*cs2 + g1s*sn2);
        float B = -LOG2E * (cs*sn*(g0s - g1s));
        float C = -0.5f * LOG2E * (g0s*sn2 + g1s*cs2);
        float m0 = mu[i*2+0], m1 = mu[i*2+1];
        float* o = pcq + i*12;
        o[0] = A;  o[1] = B;  o[2] = C;
        o[3] = -(2.0f*A*m0 + B*m1);
        o[4] = -(B*m0 + 2.0f*C*m1);
        o[5] = A*m0*m0 + B*m0*m1 + C*m1*m1;
        o[6] = filt_w[i*2+0] * INV_TWO_PI;
        o[7] = filt_w[i*2+1] * INV_TWO_PI;
        o[8] = filt_b[i] * INV_TWO_PI;
        o[9] = 0.0f; o[10] = 0.0f; o[11] = 0.0f;
    } else if (t < 320 + 16384) {
        int i  = t - 320;                      // l*4096 + c*64 + ks
        int ks = i & 63;
        float w = lin_w[(i - ks) + kperm(ks)];
        ushort_t h = bf16_hi(w);
        whi[i] = h;
        wlo[i] = bf16_hi(w - bf16_tof(h));
    } else if (t < 320 + 16384 + 1024) {
        int i  = t - (320 + 16384);            // m*64 + ks
        int m  = i >> 6, ks = i & 63;
        float w = (m < 3) ? out_w[m*64 + kperm(ks)] : 0.0f;
        ushort_t h = bf16_hi(w);
        wouthi[i] = h;
        woutlo[i] = bf16_hi(w - bf16_tof(h));
    }
}

// expanded gabor eval (x02,x11,x12 shared per pixel)
__device__ __forceinline__ float gevalp(const float* __restrict__ q,
                                        float x0, float x1,
                                        float x02, float x11, float x12) {
    f32x4 qa = *(const f32x4*)q;
    f32x4 qb = *(const f32x4*)(q + 4);
    float t = fmaf(qa[0], x02, fmaf(qa[1], x11,
              fmaf(qa[2], x12, fmaf(qa[3], x0, fmaf(qb[0], x1, qb[1])))));
    float e  = __builtin_amdgcn_exp2f(t);
    float sa = fmaf(qb[2], x0, fmaf(qb[3], x1, q[8]));
    return e * __builtin_amdgcn_sinf(sa);
}

// 4 consecutive channels starting at q (stride 12 floats)
__device__ __forceinline__ f32x4 geval4(const float* __restrict__ q,
                                        float x0, float x1,
                                        float x02, float x11, float x12) {
    f32x4 r;
    r[0] = gevalp(q,      x0, x1, x02, x11, x12);
    r[1] = gevalp(q + 12, x0, x1, x02, x11, x12);
    r[2] = gevalp(q + 24, x0, x1, x02, x11, x12);
    r[3] = gevalp(q + 36, x0, x1, x02, x11, x12);
    return r;
}

struct frag2 { s16x8 h, l; };
// build B-frag pair (hi/lo) from two C/D f32x4's (MI even, MI odd)
__device__ __forceinline__ frag2 mkfrag(f32x4 vA, f32x4 vB) {
    s16x8 fh, fl;
#define MKF_R(R) { \
    ushort_t hA = bf16_hi(vA[R]); ushort_t hB = bf16_hi(vB[R]); \
    fh[R] = (short)hA; fh[R + 4] = (short)hB; \
    fl[R]     = (short)bf16_hi(vA[R] - bf16_tof(hA)); \
    fl[R + 4] = (short)bf16_hi(vB[R] - bf16_tof(hB)); }
    MKF_R(0) MKF_R(1) MKF_R(2) MKF_R(3)
#undef MKF_R
    return {fh, fl};
}

// One wave = 64 pixels, 4 independent waves per 256-block. No LDS, no
// barriers, and NO LOCAL ARRAYS: all state is individually named variables
// (R7's arrays were never SROA-promoted -> 1.6 GB scratch traffic to HBM).
// GEMM per layer: D[c,px] = W[c,k] h[k,px], mfma_f32_16x16x32_bf16,
// 3-product split-bf16 (ah*bh + ah*bl + al*bh; al*bl ~2^-18 dropped... NOTE:
// R5-R7 kept 4th product in layers; here 3 products everywhere, error still
// ~2^-16 relative, far under threshold).
//   A frag: m = lane&15, k-slot = (lane>>4)*8 + j  (W rows, permuted cols)
//   B frag: n = lane&15 (pixel), k-slot = (lane>>4)*8 + j
//   C/D:    col n = lane&15 (pixel), row m = (lane>>4)*4 + reg (channel)
__global__ __launch_bounds__(256, 2) void gabor_mfma(
    const float* __restrict__ x, const float* __restrict__ lin_b,
    const float* __restrict__ out_b, const float* __restrict__ pcq,
    const ushort_t* __restrict__ whi, const ushort_t* __restrict__ wlo,
    const ushort_t* __restrict__ wouthi, const ushort_t* __restrict__ woutlo,
    float* __restrict__ out) {
    const int lane = threadIdx.x & 63;
    const int wid  = threadIdx.x >> 6;
    const int g    = lane >> 4;
    const int lm   = lane & 15;
    const int base = blockIdx.x * 256 + wid * 64;

    f32x4 x0v, x1v, x02v, x11v, x12v;
    int pixo0, pixo1, pixo2, pixo3;
#define LOADPX(NI) { \
    int P = base + NI*16 + lm; \
    int bb = P >> 18, pix = P & (HW2 - 1); \
    const float* xb = x + bb*(2*HW2) + pix; \
    float a = xb[0], b = xb[HW2]; \
    x0v[NI] = a; x1v[NI] = b; \
    x02v[NI] = a*a; x11v[NI] = a*b; x12v[NI] = b*b; \
    int po = bb*(3*HW2) + pix; \
    if (NI == 0) pixo0 = po; else if (NI == 1) pixo1 = po; \
    else if (NI == 2) pixo2 = po; else pixo3 = po; }
    LOADPX(0) LOADPX(1) LOADPX(2) LOADPX(3)
#undef LOADPX

    // h as B-fragments: fh_<ni>_<kc> / fl_<ni>_<kc>, all named (no arrays)
    s16x8 fh_0_0, fh_0_1, fh_1_0, fh_1_1, fh_2_0, fh_2_1, fh_3_0, fh_3_1;
    s16x8 fl_0_0, fl_0_1, fl_1_0, fl_1_1, fl_2_0, fl_2_1, fl_3_0, fl_3_1;

    // ---- layer 0: gabor at C/D positions, straight into frags ----
#define L0(NI) { \
    f32x4 v0 = geval4(pcq + (4*g)*12,      x0v[NI], x1v[NI], x02v[NI], x11v[NI], x12v[NI]); \
    f32x4 v1 = geval4(pcq + (16 + 4*g)*12, x0v[NI], x1v[NI], x02v[NI], x11v[NI], x12v[NI]); \
    f32x4 v2 = geval4(pcq + (32 + 4*g)*12, x0v[NI], x1v[NI], x02v[NI], x11v[NI], x12v[NI]); \
    f32x4 v3 = geval4(pcq + (48 + 4*g)*12, x0v[NI], x1v[NI], x02v[NI], x11v[NI], x12v[NI]); \
    frag2 tA = mkfrag(v0, v1); frag2 tB = mkfrag(v2, v3); \
    fh_##NI##_0 = tA.h; fl_##NI##_0 = tA.l; \
    fh_##NI##_1 = tB.h; fl_##NI##_1 = tB.l; }
    L0(0) L0(1) L0(2) L0(3)
#undef L0

#define BMFMA __builtin_amdgcn_mfma_f32_16x16x32_bf16
    // ---- layers 1..4 ----
#pragma unroll 1
    for (int l = 1; l <= 4; ++l) {
        const ushort_t* whl = whi + (l-1)*4096;
        const ushort_t* wll = wlo + (l-1)*4096;
        const float*    bv  = lin_b + (l-1)*64;
        const float*    pcl = pcq + l*768;

        f32x4 bb0 = *(const f32x4*)(bv +      4*g);
        f32x4 bb1 = *(const f32x4*)(bv + 16 + 4*g);
        f32x4 bb2 = *(const f32x4*)(bv + 32 + 4*g);
        f32x4 bb3 = *(const f32x4*)(bv + 48 + 4*g);
        f32x4 a_0_0 = bb0, a_0_1 = bb0, a_0_2 = bb0, a_0_3 = bb0;
        f32x4 a_1_0 = bb1, a_1_1 = bb1, a_1_2 = bb1, a_1_3 = bb1;
        f32x4 a_2_0 = bb2, a_2_1 = bb2, a_2_2 = bb2, a_2_3 = bb2;
        f32x4 a_3_0 = bb3, a_3_1 = bb3, a_3_2 = bb3, a_3_3 = bb3;

        // each W fragment pair feeds all 4 pixel tiles (12 MFMAs per load)
#define MSTEP(KC, MI) { \
        const s16x8 ah = *(const s16x8*)(whl + (MI*16 + lm)*64 + KC*32 + g*8); \
        const s16x8 al = *(const s16x8*)(wll + (MI*16 + lm)*64 + KC*32 + g*8); \
        a_##MI##_0 = BMFMA(ah, fh_0_##KC, a_##MI##_0, 0, 0, 0); \
        a_##MI##_0 = BMFMA(ah, fl_0_##KC, a_##MI##_0, 0, 0, 0); \
        a_##MI##_0 = BMFMA(al, fh_0_##KC, a_##MI##_0, 0, 0, 0); \
        a_##MI##_1 = BMFMA(ah, fh_1_##KC, a_##MI##_1, 0, 0, 0); \
        a_##MI##_1 = BMFMA(ah, fl_1_##KC, a_##MI##_1, 0, 0, 0); \
        a_##MI##_1 = BMFMA(al, fh_1_##KC, a_##MI##_1, 0, 0, 0); \
        a_##MI##_2 = BMFMA(ah, fh_2_##KC, a_##MI##_2, 0, 0, 0); \
        a_##MI##_2 = BMFMA(ah, fl_2_##KC, a_##MI##_2, 0, 0, 0); \
        a_##MI##_2 = BMFMA(al, fh_2_##KC, a_##MI##_2, 0, 0, 0); \
        a_##MI##_3 = BMFMA(ah, fh_3_##KC, a_##MI##_3, 0, 0, 0); \
        a_##MI##_3 = BMFMA(ah, fl_3_##KC, a_##MI##_3, 0, 0, 0); \
        a_##MI##_3 = BMFMA(al, fh_3_##KC, a_##MI##_3, 0, 0, 0); }
        MSTEP(0, 0) MSTEP(0, 1) MSTEP(0, 2) MSTEP(0, 3)
        MSTEP(1, 0) MSTEP(1, 1) MSTEP(1, 2) MSTEP(1, 3)
#undef MSTEP

        // epilogue: acc *= gabor (params CSE'd across the 4 pixel tiles)
#define EPI(MI) { \
        const float* qb_ = pcl + (MI*16 + 4*g)*12; \
        a_##MI##_0 *= geval4(qb_, x0v[0], x1v[0], x02v[0], x11v[0], x12v[0]); \
        a_##MI##_1 *= geval4(qb_, x0v[1], x1v[1], x02v[1], x11v[1], x12v[1]); \
        a_##MI##_2 *= geval4(qb_, x0v[2], x1v[2], x02v[2], x11v[2], x12v[2]); \
        a_##MI##_3 *= geval4(qb_, x0v[3], x1v[3], x02v[3], x11v[3], x12v[3]); }
        EPI(0) EPI(1) EPI(2) EPI(3)
#undef EPI

        // rebuild next-layer B-frags in-register (kperm identity)
#define REB(NI) { \
        frag2 tA = mkfrag(a_0_##NI, a_1_##NI); \
        frag2 tB = mkfrag(a_2_##NI, a_3_##NI); \
        fh_##NI##_0 = tA.h; fl_##NI##_0 = tA.l; \
        fh_##NI##_1 = tB.h; fl_##NI##_1 = tB.l; }
        REB(0) REB(1) REB(2) REB(3)
#undef REB
    }

    // ---- output: out[o,px] = Wout[o,k] h4[k,px] + out_b ----
    const s16x8 oh0 = *(const s16x8*)(wouthi + lm*64 +      g*8);
    const s16x8 ol0 = *(const s16x8*)(woutlo + lm*64 +      g*8);
    const s16x8 oh1 = *(const s16x8*)(wouthi + lm*64 + 32 + g*8);
    const s16x8 ol1 = *(const s16x8*)(woutlo + lm*64 + 32 + g*8);
    float ob0 = out_b[0], ob1 = out_b[1], ob2 = out_b[2];
#define OUTNI(NI, PO) { \
    f32x4 ao = (f32x4)(0.0f); \
    ao = BMFMA(oh0, fh_##NI##_0, ao, 0, 0, 0); \
    ao = BMFMA(oh0, fl_##NI##_0, ao, 0, 0, 0); \
    ao = BMFMA(ol0, fh_##NI##_0, ao, 0, 0, 0); \
    ao = BMFMA(oh1, fh_##NI##_1, ao, 0, 0, 0); \
    ao = BMFMA(oh1, fl_##NI##_1, ao, 0, 0, 0); \
    ao = BMFMA(ol1, fh_##NI##_1, ao, 0, 0, 0); \
    if (lane < 16) { \
        float* po = out + PO; \
        po[0]     = ao[0] + ob0; \
        po[HW2]   = ao[1] + ob1; \
        po[2*HW2] = ao[2] + ob2; } }
    OUTNI(0, pixo0) OUTNI(1, pixo1) OUTNI(2, pixo2) OUTNI(3, pixo3)
#undef OUTNI
#undef BMFMA
}

extern "C" void kernel_launch(void* const* d_in, const int* in_sizes, int n_in,
                              void* d_out, int out_size, void* d_ws, size_t ws_size,
                              hipStream_t stream) {
    const float* x      = (const float*)d_in[0];
    const float* filt_w = (const float*)d_in[1];
    const float* filt_b = (const float*)d_in[2];
    const float* mu     = (const float*)d_in[3];
    const float* gamma  = (const float*)d_in[4];
    const float* theta  = (const float*)d_in[5];
    const float* lin_w  = (const float*)d_in[6];
    const float* lin_b  = (const float*)d_in[7];
    const float* out_w  = (const float*)d_in[8];
    const float* out_b  = (const float*)d_in[9];

    char* ws = (char*)d_ws;
    float*    pcq    = (float*)ws;
    ushort_t* whi    = (ushort_t*)(ws + WS_WHI);
    ushort_t* wlo    = (ushort_t*)(ws + WS_WLO);
    ushort_t* wouthi = (ushort_t*)(ws + WS_WOH);
    ushort_t* woutlo = (ushort_t*)(ws + WS_WOL);

    gabor_pre<<<70, 256, 0, stream>>>(filt_w, filt_b, mu, gamma, theta,
                                      lin_w, out_w, pcq, whi, wlo, wouthi, woutlo);
    gabor_mfma<<<2048, 256, 0, stream>>>(x, lin_b, out_b, pcq, whi, wlo,
                                         wouthi, woutlo, (float*)d_out);
}